// Round 12
// baseline (44.159 us; speedup 1.0000x reference)
//
#include <hip/hip_runtime.h>
#include <hip/hip_fp16.h>

#define MARGIN 0.2f
#define WINDOW 0.25f     // compact |s| < WINDOW in pass 1
#define MU_MAX 0.045     // fast path valid iff |mean| <= MU_MAX (WINDOW - MU_MAX > MARGIN)
#define NBLK 2048
#define NTHR 256
#define WPB  (NTHR / 64) // waves per block
#define WCAP 1280        // per-wave candidate capacity (expected ~809, sigma ~26)

typedef float f32x4 __attribute__((ext_vector_type(4)));

// Lessons (R3-R5, R9, R10): NO mid-kernel __threadfence (~+220us); NO fused
// finalize via same-line atomics (~+35us); NO histogram (unexplained replay
// divergence); K2 needs max grid/TLP (512-block variant was +10us). Kernel
// boundaries are the cheap cross-block barrier; ballot-compaction is
// bit-deterministic (no atomics). Candidates half-packed: all in
// (-0.25,0.25), ulp <= 1.22e-4, final-mean error ~1e-5 << 3.17e-4 threshold.
// R12 delta vs R11: K1 input loads are NON-TEMPORAL (input is read exactly
// once; caching it only evicts the candidate array K2 wants resident).
struct Ws {
    double   p1[NBLK];                        // per-block partial sums
    double   p2[NBLK];                        // per-block partial loss sums
    unsigned counts[NBLK * WPB];              // true per-wave candidate counts
    __half   cand[(size_t)NBLK * WPB * WCAP]; // per-wave candidate segments (~21 MB)
};

__device__ __forceinline__ double block_reduce(double v, double* lds) {
    #pragma unroll
    for (int off = 32; off > 0; off >>= 1) v += __shfl_down(v, off);
    const int w = threadIdx.x >> 6;
    if ((threadIdx.x & 63) == 0) lds[w] = v;
    __syncthreads();
    double t = 0.0;
    if (threadIdx.x == 0) {
        #pragma unroll
        for (int i = 0; i < WPB; ++i) t += lds[i];
    }
    __syncthreads();
    return t;
}

// Contiguous chunk geometry: block b owns len4 float4s starting at base4.
__device__ __forceinline__ void chunk_of(long n4, long b, long& base4, long& len4) {
    const long chunk4 = n4 / NBLK, rem4 = n4 % NBLK;
    base4 = b * chunk4 + (b < rem4 ? b : rem4);
    len4  = chunk4 + (b < rem4 ? 1 : 0);
}

// ---------------------------------------------------------------------------
// Kernel A: per-block sum; if COMPACT, wave-ballot-compact |s|<WINDOW
// candidates (as __half) into fixed per-wave segments. Input loads are
// non-temporal (streamed once, never re-read on the fast path).
// ---------------------------------------------------------------------------
template<bool COMPACT>
__global__ __launch_bounds__(NTHR) void sum_kernel(
    const float* __restrict__ in, long n, Ws* __restrict__ ws) {
    __shared__ double lds[WPB];
    const long n4 = n >> 2;
    const f32x4* __restrict__ in4 = reinterpret_cast<const f32x4*>(in);
    long base4, len4;
    chunk_of(n4, blockIdx.x, base4, len4);
    const int tid = threadIdx.x;
    const unsigned lane =
        __builtin_amdgcn_mbcnt_hi(~0u, __builtin_amdgcn_mbcnt_lo(~0u, 0u));
    const unsigned long long below = (1ull << lane) - 1ull;

    __half* seg = nullptr;
    unsigned wbase = 0;
    if (COMPACT)
        seg = ws->cand + (size_t)(blockIdx.x * WPB + (tid >> 6)) * WCAP;

    float s = 0.0f;
    const long rounds = (len4 + NTHR - 1) / NTHR;   // wave-uniform trip count
    for (long r = 0; r < rounds; ++r) {
        const long k = r * NTHR + tid;
        const bool act = (k < len4);
        f32x4 v;
        if (act) v = __builtin_nontemporal_load(&in4[base4 + k]);
        else     v = (f32x4){0.f, 0.f, 0.f, 0.f};
        if (COMPACT) {
            #pragma unroll
            for (int c = 0; c < 4; ++c) {
                const float e = v[c];
                const bool cand = act && (fabsf(e) < WINDOW);
                const unsigned long long m = __ballot(cand);
                if (cand) {
                    const unsigned off = wbase + (unsigned)__popcll(m & below);
                    if (off < WCAP) seg[off] = __float2half(e);
                }
                wbase += (unsigned)__popcll(m);
            }
        }
        s += (v[0] + v[1]) + (v[2] + v[3]);
    }
    if (COMPACT && (tid & 63) == 0)
        ws->counts[blockIdx.x * WPB + (tid >> 6)] = wbase;  // TRUE count

    if (blockIdx.x == 0) {   // scalar tail (n % 4)
        for (long j = (n4 << 2) + tid; j < n; j += NTHR) s += in[j];
    }
    const double t = block_reduce((double)s, lds);
    if (tid == 0) ws->p1[blockIdx.x] = t;
}

// ---------------------------------------------------------------------------
// Kernel B (byte-identical to R11): mean from p1, then loss. Fast path sums
// candidates (__half2-vectorized); fallbacks (|mean|>MU_MAX grid-wide, or
// per-block segment overflow) rescan the block's own contiguous chunk.
// Exactness: excluded elements have |s| >= WINDOW and |mean| <= MU_MAX ->
// |s-mean| >= 0.205 > MARGIN -> loss exactly 0.
// ---------------------------------------------------------------------------
template<bool TRY_FAST>
__global__ __launch_bounds__(NTHR) void loss_kernel(
    const float* __restrict__ in, long n, Ws* __restrict__ ws) {
    __shared__ double lds[WPB];
    const int tid = threadIdx.x;

    double m = 0.0;
    for (int k = tid; k < NBLK; k += NTHR) m += ws->p1[k];
    m = block_reduce(m, lds);
    __shared__ double s_mean;
    if (tid == 0) s_mean = m / (double)n;
    __syncthreads();
    const float mean = (float)s_mean;

    const long n4 = n >> 2;
    const float4* __restrict__ in4 = reinterpret_cast<const float4*>(in);

    bool fast = false;
    if (TRY_FAST) {
        __shared__ int s_ovf;
        if (tid == 0) {
            int of = 0;
            #pragma unroll
            for (int w = 0; w < WPB; ++w)
                of |= (ws->counts[blockIdx.x * WPB + w] > WCAP) ? 1 : 0;
            s_ovf = of;
        }
        __syncthreads();
        fast = (fabs(s_mean) <= (double)MU_MAX) && (s_ovf == 0);
    }

    float s = 0.0f;
    if (fast) {
        const int wave = tid >> 6, lane = tid & 63;
        const unsigned cnt = ws->counts[blockIdx.x * WPB + wave];
        const __half* __restrict__ seg =
            ws->cand + (size_t)(blockIdx.x * WPB + wave) * WCAP;
        // Vectorized pair loads (seg is 4B-aligned: WCAP even, struct aligned)
        const __half2* __restrict__ seg2 =
            reinterpret_cast<const __half2*>(seg);
        const unsigned npair = cnt >> 1;
        for (unsigned j = lane; j < npair; j += 64) {
            const float2 f = __half22float2(seg2[j]);
            s += fmaxf(MARGIN - fabsf(f.x - mean), 0.0f)
               + fmaxf(MARGIN - fabsf(f.y - mean), 0.0f);
        }
        if ((cnt & 1u) && lane == 0)
            s += fmaxf(MARGIN - fabsf(__half2float(seg[cnt - 1]) - mean), 0.0f);
    } else {
        long base4, len4;
        chunk_of(n4, blockIdx.x, base4, len4);
        for (long k = tid; k < len4; k += NTHR) {
            float4 v = in4[base4 + k];
            s += fmaxf(MARGIN - fabsf(v.x - mean), 0.0f)
               + fmaxf(MARGIN - fabsf(v.y - mean), 0.0f);
            s += fmaxf(MARGIN - fabsf(v.z - mean), 0.0f)
               + fmaxf(MARGIN - fabsf(v.w - mean), 0.0f);
        }
    }
    if (blockIdx.x == 0) {   // scalar tail (n % 4)
        for (long j = (n4 << 2) + tid; j < n; j += NTHR)
            s += fmaxf(MARGIN - fabsf(in[j] - mean), 0.0f);
    }
    const double t = block_reduce((double)s, lds);
    if (tid == 0) ws->p2[blockIdx.x] = t;
}

// ---------------------------------------------------------------------------
// Kernel C: reduce p2 -> out (single block; kernel boundary = cheap barrier)
// ---------------------------------------------------------------------------
__global__ __launch_bounds__(NTHR) void finalize_kernel(
    const Ws* __restrict__ ws, float* __restrict__ out, long n) {
    __shared__ double lds[WPB];
    double m = 0.0;
    for (int k = threadIdx.x; k < NBLK; k += NTHR) m += ws->p2[k];
    m = block_reduce(m, lds);
    if (threadIdx.x == 0) out[0] = (float)(m / (double)n);
}

extern "C" void kernel_launch(void* const* d_in, const int* in_sizes, int n_in,
                              void* d_out, int out_size, void* d_ws, size_t ws_size,
                              hipStream_t stream) {
    const float* sims = (const float*)d_in[0];
    const long n = (long)in_sizes[0];
    Ws* ws = (Ws*)d_ws;
    float* out = (float*)d_out;

    if (ws_size >= sizeof(Ws)) {
        sum_kernel<true><<<NBLK, NTHR, 0, stream>>>(sims, n, ws);
        loss_kernel<true><<<NBLK, NTHR, 0, stream>>>(sims, n, ws);
    } else {
        // classic 2-full-pass path (touches only p1/p2)
        sum_kernel<false><<<NBLK, NTHR, 0, stream>>>(sims, n, ws);
        loss_kernel<false><<<NBLK, NTHR, 0, stream>>>(sims, n, ws);
    }
    finalize_kernel<<<1, NTHR, 0, stream>>>(ws, out, n);
}

// Round 13
// 40.256 us; speedup vs baseline: 1.0970x; 1.0970x over previous
//
#include <hip/hip_runtime.h>
#include <hip/hip_fp16.h>

#define MARGIN 0.2f
#define WINDOW 0.25f     // compact |s| < WINDOW in pass 1
#define MU_MAX 0.045     // fast path valid iff |mean| <= MU_MAX (WINDOW - MU_MAX > MARGIN)
#define NBLK 2048
#define NTHR 256
#define WPB  (NTHR / 64) // waves per block
#define WCAP 1280        // per-wave candidate capacity (expected ~809, sigma ~26)

// Lessons (R3-R5, R9, R10, R12): NO mid-kernel __threadfence (~+220us); NO
// fused finalize via same-line atomics (~+35us); NO histogram (unexplained
// replay divergence); K2 needs max grid/TLP (512-block variant was +10us);
// NO nontemporal loads on the streaming pass (+4us, R12). Kernel boundaries
// are the cheap cross-block barrier; ballot-compaction is bit-deterministic
// (no atomics). Candidates half-packed: all in (-0.25,0.25), ulp <= 1.22e-4,
// final-mean error ~1e-5 << 3.17e-4 threshold.
// R13 = exact revert to R11 champion (40.26 us).
struct Ws {
    double   p1[NBLK];                        // per-block partial sums
    double   p2[NBLK];                        // per-block partial loss sums
    unsigned counts[NBLK * WPB];              // true per-wave candidate counts
    __half   cand[(size_t)NBLK * WPB * WCAP]; // per-wave candidate segments (~21 MB)
};

__device__ __forceinline__ double block_reduce(double v, double* lds) {
    #pragma unroll
    for (int off = 32; off > 0; off >>= 1) v += __shfl_down(v, off);
    const int w = threadIdx.x >> 6;
    if ((threadIdx.x & 63) == 0) lds[w] = v;
    __syncthreads();
    double t = 0.0;
    if (threadIdx.x == 0) {
        #pragma unroll
        for (int i = 0; i < WPB; ++i) t += lds[i];
    }
    __syncthreads();
    return t;
}

// Contiguous chunk geometry: block b owns len4 float4s starting at base4.
__device__ __forceinline__ void chunk_of(long n4, long b, long& base4, long& len4) {
    const long chunk4 = n4 / NBLK, rem4 = n4 % NBLK;
    base4 = b * chunk4 + (b < rem4 ? b : rem4);
    len4  = chunk4 + (b < rem4 ? 1 : 0);
}

// ---------------------------------------------------------------------------
// Kernel A: per-block sum; if COMPACT, wave-ballot-compact |s|<WINDOW
// candidates (as __half) into fixed per-wave segments.
// ---------------------------------------------------------------------------
template<bool COMPACT>
__global__ __launch_bounds__(NTHR) void sum_kernel(
    const float* __restrict__ in, long n, Ws* __restrict__ ws) {
    __shared__ double lds[WPB];
    const long n4 = n >> 2;
    const float4* __restrict__ in4 = reinterpret_cast<const float4*>(in);
    long base4, len4;
    chunk_of(n4, blockIdx.x, base4, len4);
    const int tid = threadIdx.x;
    const unsigned lane =
        __builtin_amdgcn_mbcnt_hi(~0u, __builtin_amdgcn_mbcnt_lo(~0u, 0u));
    const unsigned long long below = (1ull << lane) - 1ull;

    __half* seg = nullptr;
    unsigned wbase = 0;
    if (COMPACT)
        seg = ws->cand + (size_t)(blockIdx.x * WPB + (tid >> 6)) * WCAP;

    float s = 0.0f;
    const long rounds = (len4 + NTHR - 1) / NTHR;   // wave-uniform trip count
    for (long r = 0; r < rounds; ++r) {
        const long k = r * NTHR + tid;
        const bool act = (k < len4);
        float4 v = act ? in4[base4 + k] : make_float4(0.f, 0.f, 0.f, 0.f);
        if (COMPACT) {
            const float e[4] = {v.x, v.y, v.z, v.w};
            #pragma unroll
            for (int c = 0; c < 4; ++c) {
                const bool cand = act && (fabsf(e[c]) < WINDOW);
                const unsigned long long m = __ballot(cand);
                if (cand) {
                    const unsigned off = wbase + (unsigned)__popcll(m & below);
                    if (off < WCAP) seg[off] = __float2half(e[c]);
                }
                wbase += (unsigned)__popcll(m);
            }
        }
        s += (v.x + v.y) + (v.z + v.w);
    }
    if (COMPACT && (tid & 63) == 0)
        ws->counts[blockIdx.x * WPB + (tid >> 6)] = wbase;  // TRUE count

    if (blockIdx.x == 0) {   // scalar tail (n % 4)
        for (long j = (n4 << 2) + tid; j < n; j += NTHR) s += in[j];
    }
    const double t = block_reduce((double)s, lds);
    if (tid == 0) ws->p1[blockIdx.x] = t;
}

// ---------------------------------------------------------------------------
// Kernel B: mean from p1, then loss. Fast path sums candidates only
// (__half2-vectorized); fallbacks (|mean|>MU_MAX grid-wide, or per-block
// segment overflow) rescan the block's own contiguous chunk. Exactness:
// excluded elements have |s| >= WINDOW and |mean| <= MU_MAX ->
// |s-mean| >= 0.205 > MARGIN -> loss exactly 0.
// ---------------------------------------------------------------------------
template<bool TRY_FAST>
__global__ __launch_bounds__(NTHR) void loss_kernel(
    const float* __restrict__ in, long n, Ws* __restrict__ ws) {
    __shared__ double lds[WPB];
    const int tid = threadIdx.x;

    double m = 0.0;
    for (int k = tid; k < NBLK; k += NTHR) m += ws->p1[k];
    m = block_reduce(m, lds);
    __shared__ double s_mean;
    if (tid == 0) s_mean = m / (double)n;
    __syncthreads();
    const float mean = (float)s_mean;

    const long n4 = n >> 2;
    const float4* __restrict__ in4 = reinterpret_cast<const float4*>(in);

    bool fast = false;
    if (TRY_FAST) {
        __shared__ int s_ovf;
        if (tid == 0) {
            int of = 0;
            #pragma unroll
            for (int w = 0; w < WPB; ++w)
                of |= (ws->counts[blockIdx.x * WPB + w] > WCAP) ? 1 : 0;
            s_ovf = of;
        }
        __syncthreads();
        fast = (fabs(s_mean) <= (double)MU_MAX) && (s_ovf == 0);
    }

    float s = 0.0f;
    if (fast) {
        const int wave = tid >> 6, lane = tid & 63;
        const unsigned cnt = ws->counts[blockIdx.x * WPB + wave];
        const __half* __restrict__ seg =
            ws->cand + (size_t)(blockIdx.x * WPB + wave) * WCAP;
        // Vectorized pair loads (seg is 4B-aligned: WCAP even, struct aligned)
        const __half2* __restrict__ seg2 =
            reinterpret_cast<const __half2*>(seg);
        const unsigned npair = cnt >> 1;
        for (unsigned j = lane; j < npair; j += 64) {
            const float2 f = __half22float2(seg2[j]);
            s += fmaxf(MARGIN - fabsf(f.x - mean), 0.0f)
               + fmaxf(MARGIN - fabsf(f.y - mean), 0.0f);
        }
        if ((cnt & 1u) && lane == 0)
            s += fmaxf(MARGIN - fabsf(__half2float(seg[cnt - 1]) - mean), 0.0f);
    } else {
        long base4, len4;
        chunk_of(n4, blockIdx.x, base4, len4);
        for (long k = tid; k < len4; k += NTHR) {
            float4 v = in4[base4 + k];
            s += fmaxf(MARGIN - fabsf(v.x - mean), 0.0f)
               + fmaxf(MARGIN - fabsf(v.y - mean), 0.0f);
            s += fmaxf(MARGIN - fabsf(v.z - mean), 0.0f)
               + fmaxf(MARGIN - fabsf(v.w - mean), 0.0f);
        }
    }
    if (blockIdx.x == 0) {   // scalar tail (n % 4)
        for (long j = (n4 << 2) + tid; j < n; j += NTHR)
            s += fmaxf(MARGIN - fabsf(in[j] - mean), 0.0f);
    }
    const double t = block_reduce((double)s, lds);
    if (tid == 0) ws->p2[blockIdx.x] = t;
}

// ---------------------------------------------------------------------------
// Kernel C: reduce p2 -> out (single block; kernel boundary = cheap barrier)
// ---------------------------------------------------------------------------
__global__ __launch_bounds__(NTHR) void finalize_kernel(
    const Ws* __restrict__ ws, float* __restrict__ out, long n) {
    __shared__ double lds[WPB];
    double m = 0.0;
    for (int k = threadIdx.x; k < NBLK; k += NTHR) m += ws->p2[k];
    m = block_reduce(m, lds);
    if (threadIdx.x == 0) out[0] = (float)(m / (double)n);
}

extern "C" void kernel_launch(void* const* d_in, const int* in_sizes, int n_in,
                              void* d_out, int out_size, void* d_ws, size_t ws_size,
                              hipStream_t stream) {
    const float* sims = (const float*)d_in[0];
    const long n = (long)in_sizes[0];
    Ws* ws = (Ws*)d_ws;
    float* out = (float*)d_out;

    if (ws_size >= sizeof(Ws)) {
        sum_kernel<true><<<NBLK, NTHR, 0, stream>>>(sims, n, ws);
        loss_kernel<true><<<NBLK, NTHR, 0, stream>>>(sims, n, ws);
    } else {
        // classic 2-full-pass path (touches only p1/p2)
        sum_kernel<false><<<NBLK, NTHR, 0, stream>>>(sims, n, ws);
        loss_kernel<false><<<NBLK, NTHR, 0, stream>>>(sims, n, ws);
    }
    finalize_kernel<<<1, NTHR, 0, stream>>>(ws, out, n);
}